// Round 8
// baseline (845.469 us; speedup 1.0000x reference)
//
#include <hip/hip_runtime.h>
#include <math.h>

#define BB 4
#define HH 16
#define SS 8192
#define HDD 64
#define DD 1024
#define MEM 65536
#define KT 10
#define AUGROWS (SS + KT)

// ---------------- output offsets (floats) ----------------
static const long O0 = 0;          // inputs      33554432
static const long O1 = 33554432;   // q           33554432
static const long O2 = 67108864;   // aug_k       33595392 (B,H,S+KT,HD)
static const long O3 = 100704256;  // aug_v       33595392
static const long O4 = 134299648;  // aug_mask    32808
static const long O5 = 134332456;  // aug_pos     32808
static const long O6 = 134365264;  // new_events  33554432
static const long O7 = 167919696;  // event_len   32768

// ---------------- ws layout (bytes) ----------------
// 0        double surprise[B*S]        262144
// 262144   float  sims[B*MEM]          1048576  -> 1310720
// 1310720  int    bpos[B*S]            131072   -> 1441792
// 1441792  int    nseg[B]
// 1441824  int    idx[B*KT]
// 1442304  float  cval[B*16*10]        2560
// 1444864  int    cidx[B*16*10]        2560     -> 1447424
// 1447424  int    counters[16]         64       (3 barrier cnt/gen pairs)
// 1572864  double partial[B*H*S]       4194304  -> 5767168  (layout [b][h][s])
#define WS_NEED_FUSED 5767168UL

#define N4REG 8388608L   // float4 per 128MB region
#define NB 768           // persistent grid (3 blocks/CU; capacity 4/CU via launch_bounds)
#define NTH 256
#define GSTRIDE ((long)NB * NTH)  // 196608

typedef float __attribute__((ext_vector_type(4))) f4v;

static __device__ __forceinline__ void nt_store4(float4* p, float4 v) {
    f4v t; t.x = v.x; t.y = v.y; t.z = v.z; t.w = v.w;
    __builtin_nontemporal_store(t, (f4v*)p);
}
static __device__ __forceinline__ float4 nt_load4(const float4* p) {
    f4v t = __builtin_nontemporal_load((const f4v*)p);
    float4 v; v.x = t.x; v.y = t.y; v.z = t.z; v.w = t.w;
    return v;
}

// single-use global barrier (per launch); cnt/gen zeroed by memset each launch
static __device__ __forceinline__ void gbar(int* cnt, int* gen) {
    __syncthreads();
    __threadfence();
    if (threadIdx.x == 0) {
        int g = atomicAdd(gen, 0);
        if (atomicAdd(cnt, 1) == NB - 1) {
            atomicAdd(gen, 1);
        } else {
            while (atomicAdd(gen, 0) == g) __builtin_amdgcn_s_sleep(8);
        }
    }
    __syncthreads();
    __threadfence();
}

// fallback (small ws): standalone surprise pass reading k directly
__global__ __launch_bounds__(256) void surprise_fallback_kernel(
        const float* __restrict__ k, double* __restrict__ surprise) {
    int wid = (int)(((long)blockIdx.x * blockDim.x + threadIdx.x) >> 6);
    int lane = threadIdx.x & 63;
    if (wid >= BB * SS) return;
    int b = wid >> 13;
    int s = wid & (SS - 1);
    double acc = 0.0;
    if (s > 0) {
        const float* kb = k + (long)b * HH * SS * HDD;
        for (int h = 0; h < HH; ++h) {
            long off = ((long)h * SS + s) * HDD + lane;
            double d = (double)kb[off] - (double)kb[off - HDD];
            acc += d * d;
        }
        for (int m = 32; m >= 1; m >>= 1) acc += __shfl_xor(acc, m, 64);
    }
    if (lane == 0) surprise[wid] = (s == 0) ? 0.0 : sqrt(acc);
}

// ------------------------------------------------------------------
// Persistent mega-kernel. Phases separated by global barriers:
//  A: sequential-region streaming copies (inputs,q,k+partials,v) + sims + maskpos
//  B1: surprise h-reduce (blocks 0..127) || topk_part (blocks 128..191)
//  B2: stats+scan (blocks 0..3) || topk_merge (blocks 4..7)
//  C: segment means (reads clean in_k) + zero rows + gather fronts
__global__ __launch_bounds__(256, 4) void mega_kernel(
        const float4* __restrict__ in0, const float4* __restrict__ q,
        const float4* __restrict__ k4, const float4* __restrict__ v,
        const float4* __restrict__ events4, const float* __restrict__ amask,
        const void* __restrict__ seqp, float* __restrict__ out,
        double* __restrict__ partial, double* __restrict__ surprise,
        float* __restrict__ sims, int* __restrict__ bpos,
        int* __restrict__ nseg, float* __restrict__ cval,
        int* __restrict__ cidx, int* __restrict__ idxw,
        int* __restrict__ counters, int fused) {
    __shared__ __align__(16) char smem[20992];
    int blk = blockIdx.x;
    int tid = threadIdx.x;
    int gtid = blk * NTH + tid;
    float4* out4 = (float4*)out;
    const float* eventsf = (const float*)events4;

    // ================= phase A =================
    // A.1 streaming copies: one region at a time (grid-wide moving window)
    for (long i = gtid; i < 4 * N4REG; i += GSTRIDE) {
        int region = (int)(i >> 23);
        long rel = i & (N4REG - 1);
        if (region == 0) {
            nt_store4(out4 + (O0 >> 2) + rel, nt_load4(in0 + rel));
        } else if (region == 1) {
            nt_store4(out4 + (O1 >> 2) + rel, nt_load4(q + rel));
        } else if (region == 3) {
            long chunk = rel >> 17;  // (b*H+h), 131072 float4 per slice
            long r = rel & 131071;
            nt_store4(out4 + (O3 >> 2) + chunk * 131232L + 160 + r,
                      nt_load4(v + rel));
        } else {  // region 2: k -> aug_k interior (plain) + surprise partials
            long chunk = rel >> 17;
            long r = rel & 131071;
            float4 cur = k4[rel];
            out4[(O2 >> 2) + chunk * 131232L + 160 + r] = cur;
            if (fused) {
                int s = (int)(r >> 4);  // 16 float4 per row
                if (s > 0) {
                    float4 pv = k4[rel - 16];
                    double dx = (double)cur.x - (double)pv.x;
                    double dy = (double)cur.y - (double)pv.y;
                    double dz = (double)cur.z - (double)pv.z;
                    double dw = (double)cur.w - (double)pv.w;
                    double acc = dx * dx + dy * dy + dz * dz + dw * dw;
                    acc += __shfl_xor(acc, 1, 64);
                    acc += __shfl_xor(acc, 2, 64);
                    acc += __shfl_xor(acc, 4, 64);
                    acc += __shfl_xor(acc, 8, 64);
                    if ((tid & 15) == 0)
                        partial[chunk * SS + s] = acc;  // [b][h][s]: coalesced
                }
            }
        }
    }
    // A.2 sims: stage queries in LDS, one event row per wave per iteration
    {
        float4(*qls4)[256] = (float4(*)[256])smem;
        for (int j = tid; j < BB * 256; j += 256) {
            int b = j >> 8;
            int f4i = j & 255;
            qls4[b][f4i] =
                k4[((long)(b * HH + (f4i >> 4)) * SS + (SS - 1)) * 16 + (f4i & 15)];
        }
        __syncthreads();
        int w = tid >> 6;
        int lane = tid & 63;
        for (long e = blk * 4 + w; e < MEM; e += NB * 4) {
            const float4* er = events4 + e * 256;
            float en = 0.f, d0 = 0.f, d1 = 0.f, d2 = 0.f, d3 = 0.f;
#pragma unroll
            for (int it = 0; it < 4; ++it) {
                int j4 = lane + it * 64;
                float4 ev = nt_load4(er + j4);
                en += ev.x * ev.x + ev.y * ev.y + ev.z * ev.z + ev.w * ev.w;
                float4 q0 = qls4[0][j4];
                d0 += ev.x * q0.x + ev.y * q0.y + ev.z * q0.z + ev.w * q0.w;
                float4 q1 = qls4[1][j4];
                d1 += ev.x * q1.x + ev.y * q1.y + ev.z * q1.z + ev.w * q1.w;
                float4 q2 = qls4[2][j4];
                d2 += ev.x * q2.x + ev.y * q2.y + ev.z * q2.z + ev.w * q2.w;
                float4 q3 = qls4[3][j4];
                d3 += ev.x * q3.x + ev.y * q3.y + ev.z * q3.z + ev.w * q3.w;
            }
            for (int m = 32; m >= 1; m >>= 1) {
                en += __shfl_xor(en, m, 64);
                d0 += __shfl_xor(d0, m, 64);
                d1 += __shfl_xor(d1, m, 64);
                d2 += __shfl_xor(d2, m, 64);
                d3 += __shfl_xor(d3, m, 64);
            }
            if (lane == 0) {
                float enn = fmaxf(sqrtf(en), 1e-8f);
                sims[0 * (long)MEM + e] = d0 / enn;
                sims[1 * (long)MEM + e] = d1 / enn;
                sims[2 * (long)MEM + e] = d2 / enn;
                sims[3 * (long)MEM + e] = d3 / enn;
            }
        }
    }
    // A.3 mask / positions
    {
        int iv = ((const int*)seqp)[0];
        int seqlen = (iv > 0 && iv < (1 << 24)) ? iv
                                                : (int)(((const float*)seqp)[0]);
        int cp = seqlen - 1;
        for (int i = gtid; i < BB * AUGROWS; i += (int)GSTRIDE) {
            int b = i / AUGROWS;
            int t = i - b * AUGROWS;
            out[O4 + i] = (t < KT) ? 1.0f : amask[(long)b * SS + t - KT];
            out[O5 + i] = (t < KT) ? (float)(cp - KT + t) : (float)(t - KT);
        }
    }
    gbar(&counters[0], &counters[1]);

    // ================= phase B1 =================
    if (fused) {
        for (int t = gtid; t < BB * SS; t += (int)GSTRIDE) {
            int s = t & (SS - 1);
            int b = t >> 13;
            double acc = 0.0;
            if (s > 0) {
#pragma unroll
                for (int h = 0; h < HH; ++h)
                    acc += partial[(((long)(b * HH + h)) << 13) + s];
            }
            surprise[t] = (s == 0) ? 0.0 : sqrt(acc);
        }
    }
    if (blk >= 128 && blk < 192) {
        int g = blk - 128;  // b*16 + part
        int b = g >> 4;
        int part = g & 15;
        const float* sb = sims + (long)b * MEM + part * 4096;
        float(*lv)[KT] = (float(*)[KT])smem;
        int(*li)[KT] = (int(*)[KT])(smem + 10240);
        float val[KT];
        int idx[KT];
#pragma unroll
        for (int p = 0; p < KT; ++p) { val[p] = -INFINITY; idx[p] = 0x7fffffff; }
        for (int it = 0; it < 16; ++it) {
            int e = tid + it * 256;  // increasing per thread
            float vv = sb[e];
            if (vv > val[KT - 1]) {
#pragma unroll
                for (int p = KT - 1; p >= 1; --p) {
                    if (vv > val[p - 1]) {
                        val[p] = val[p - 1];
                        idx[p] = idx[p - 1];
                    } else {
                        val[p] = vv;
                        idx[p] = e;
                        vv = -INFINITY;
                    }
                }
                if (vv != -INFINITY) { val[0] = vv; idx[0] = e; }
            }
        }
#pragma unroll
        for (int p = 0; p < KT; ++p) { lv[tid][p] = val[p]; li[tid][p] = idx[p]; }
        for (int off = 128; off >= 1; off >>= 1) {
            __syncthreads();
            if (tid < off) {
                float a_[KT], b_[KT], m_[KT];
                int ai_[KT], bi_[KT], mi_[KT];
#pragma unroll
                for (int p = 0; p < KT; ++p) {
                    a_[p] = lv[tid][p];
                    ai_[p] = li[tid][p];
                    b_[p] = lv[tid + off][p];
                    bi_[p] = li[tid + off][p];
                }
                int pa = 0, pb = 0;
#pragma unroll
                for (int p = 0; p < KT; ++p) {
                    bool ta = (a_[pa] > b_[pb]) ||
                              (a_[pa] == b_[pb] && ai_[pa] < bi_[pb]);
                    if (ta) { m_[p] = a_[pa]; mi_[p] = ai_[pa]; ++pa; }
                    else    { m_[p] = b_[pb]; mi_[p] = bi_[pb]; ++pb; }
                }
#pragma unroll
                for (int p = 0; p < KT; ++p) { lv[tid][p] = m_[p]; li[tid][p] = mi_[p]; }
            }
        }
        __syncthreads();
        if (tid == 0) {
#pragma unroll
            for (int p = 0; p < KT; ++p) {
                cval[g * KT + p] = lv[0][p];
                cidx[g * KT + p] = part * 4096 + li[0][p];
            }
        }
    }
    gbar(&counters[2], &counters[3]);

    // ================= phase B2 =================
    if (blk < 4) {
        // stats + scan; replicates the 1024-thread summation order bit-exactly
        int b = blk;
        const double* sp = surprise + (long)b * SS;
        double* sd = (double*)smem;        // [1024]
        int* si = (int*)(smem + 8192);     // [256]
        for (int p = 0; p < 4; ++p) {
            int vt = tid + 256 * p;
            double sum = 0.0;
            for (int j = 0; j < 8; ++j) sum += sp[vt * 8 + j];
            sd[vt] = sum;
        }
        __syncthreads();
        for (int off = 512; off >= 1; off >>= 1) {
            for (int p = 0; p < 4; ++p) {
                int vt = tid + 256 * p;
                if (vt < off) sd[vt] += sd[vt + off];
            }
            __syncthreads();
        }
        double mean = sd[0] / SS;
        __syncthreads();
        for (int p = 0; p < 4; ++p) {
            int vt = tid + 256 * p;
            double vs = 0.0;
            for (int j = 0; j < 8; ++j) {
                double d = sp[vt * 8 + j] - mean;
                vs += d * d;
            }
            sd[vt] = vs;
        }
        __syncthreads();
        for (int off = 512; off >= 1; off >>= 1) {
            for (int p = 0; p < 4; ++p) {
                int vt = tid + 256 * p;
                if (vt < off) sd[vt] += sd[vt + off];
            }
            __syncthreads();
        }
        double thr = mean + 0.5 * sqrt(sd[0] / (SS - 1));
        __syncthreads();
        int s0 = tid * 32;
        int cnt = 0;
        for (int j = 0; j < 32; ++j) {
            int s = s0 + j;
            cnt += (s == SS - 1) || (sp[s] > thr);
        }
        si[tid] = cnt;
        __syncthreads();
        for (int off = 1; off < 256; off <<= 1) {
            int vv = 0;
            if (tid >= off) vv = si[tid - off];
            __syncthreads();
            si[tid] += vv;
            __syncthreads();
        }
        int run = si[tid] - cnt;  // exclusive prefix
        for (int j = 0; j < 32; ++j) {
            int s = s0 + j;
            if ((s == SS - 1) || (sp[s] > thr)) {
                bpos[(long)b * SS + run] = s;
                ++run;
            }
        }
        if (tid == 255) nseg[b] = si[255];
    } else if (blk < 8) {
        int b = blk - 4;
        float* mv = (float*)smem;          // [160]
        int* mi = (int*)(smem + 1024);     // [160]
        if (tid < 160) {
            mv[tid] = cval[b * 160 + tid];
            mi[tid] = cidx[b * 160 + tid];
        }
        __syncthreads();
        if (tid == 0) {
            for (int p = 0; p < KT; ++p) {
                float best = -INFINITY;
                int bi = 0x7fffffff;
                int bslot = 0;
                for (int j = 0; j < 160; ++j) {
                    if (mv[j] > best || (mv[j] == best && mi[j] < bi)) {
                        best = mv[j];
                        bi = mi[j];
                        bslot = j;
                    }
                }
                idxw[b * KT + p] = bi;
                mv[bslot] = -INFINITY;
                mi[bslot] = 0x7fffffff;
            }
        }
    }
    gbar(&counters[4], &counters[5]);

    // ================= phase C =================
    const float4 z4 = make_float4(0.f, 0.f, 0.f, 0.f);
    for (int slot = blk; slot < BB * SS + BB * KT; slot += NB) {
        if (slot < BB * SS) {
            int b = slot >> 13;
            int j = slot & (SS - 1);
            int ns = nseg[b];
            float4* row = (float4*)(out + O6) + ((long)b * SS + j) * 256;
            if (j >= ns) {
                nt_store4(row + tid, z4);
                if (tid == 0) out[O7 + (long)b * SS + j] = 0.0f;
            } else {
                int start = (j == 0) ? 0 : bpos[(long)b * SS + j - 1] + 1;
                int end = bpos[(long)b * SS + j];
                const float4* kb =
                    k4 + ((long)(b * HH + (tid >> 4)) * SS) * 16 + (tid & 15);
                double a0 = 0.0, a1 = 0.0, a2 = 0.0, a3 = 0.0;
                for (int s = start; s <= end; ++s) {
                    float4 x = kb[(long)s * 16];
                    a0 += (double)x.x;
                    a1 += (double)x.y;
                    a2 += (double)x.z;
                    a3 += (double)x.w;
                }
                double inv = 1.0 / (double)(end - start + 1);
                nt_store4(row + tid,
                          make_float4((float)(a0 * inv), (float)(a1 * inv),
                                      (float)(a2 * inv), (float)(a3 * inv)));
                if (tid == 0)
                    out[O7 + (long)b * SS + j] = (float)(end - start + 1);
            }
        } else {
            int g = slot - BB * SS;
            int b = g / KT;
            int t = g % KT;
            int ev = idxw[b * KT + t];
#pragma unroll
            for (int c = 0; c < 4; ++c) {
                int j = tid + c * 256;
                float vv = eventsf[(long)ev * DD + j];
                int h = j >> 6;
                int d = j & 63;
                long dst = (((long)b * HH + h) * AUGROWS + t) * HDD + d;
                out[O2 + dst] = vv;
                out[O3 + dst] = vv;
            }
        }
    }
}

extern "C" void kernel_launch(void* const* d_in, const int* in_sizes, int n_in,
                              void* d_out, int out_size, void* d_ws, size_t ws_size,
                              hipStream_t stream) {
    const float* in_inputs = (const float*)d_in[0];
    const float* in_q = (const float*)d_in[1];
    const float* in_k = (const float*)d_in[2];
    const float* in_v = (const float*)d_in[3];
    const float* in_amask = (const float*)d_in[4];
    const float* in_events = (const float*)d_in[5];
    const void* in_seq = d_in[6];
    float* out = (float*)d_out;

    char* ws = (char*)d_ws;
    double* surprise = (double*)ws;
    float* sims = (float*)(ws + 262144);
    int* bpos = (int*)(ws + 1310720);
    int* nseg = (int*)(ws + 1441792);
    int* idxw = (int*)(ws + 1441824);
    float* cval = (float*)(ws + 1442304);
    int* cidx = (int*)(ws + 1444864);
    int* counters = (int*)(ws + 1447424);
    double* partial = (double*)(ws + 1572864);

    const int fused = (ws_size >= WS_NEED_FUSED) ? 1 : 0;

    hipMemsetAsync(counters, 0, 64, stream);
    if (!fused)
        surprise_fallback_kernel<<<8192, 256, 0, stream>>>(in_k, surprise);
    mega_kernel<<<NB, NTH, 0, stream>>>(
        (const float4*)in_inputs, (const float4*)in_q, (const float4*)in_k,
        (const float4*)in_v, (const float4*)in_events, in_amask, in_seq, out,
        partial, surprise, sims, bpos, nseg, cval, cidx, idxw, counters, fused);
}